// Round 8
// baseline (1379.178 us; speedup 1.0000x reference)
//
#include <hip/hip_runtime.h>

typedef float v4f __attribute__((ext_vector_type(4)));

static constexpr float EPS = 1e-6f;

// DPP partial-sum step: x += dpp_move(x); out-of-bounds lanes contribute 0.
#define DPP_ADD(x, ctrl, rmask)                                               \
  x += __builtin_bit_cast(float, __builtin_amdgcn_update_dpp(                 \
           0, __builtin_bit_cast(int, x), ctrl, rmask, 0xf, true))

// Full wave64 sum, 4 independent values interleaved (a's chain depth stays 6;
// b,c,d fill a's dependent-latency slots). Lane 63 ends with each total.
#define WAVE_RED4(a, b, c, d)                                                 \
  do {                                                                        \
    DPP_ADD(a, 0x111, 0xf); DPP_ADD(b, 0x111, 0xf);                           \
    DPP_ADD(c, 0x111, 0xf); DPP_ADD(d, 0x111, 0xf);                           \
    DPP_ADD(a, 0x112, 0xf); DPP_ADD(b, 0x112, 0xf);                           \
    DPP_ADD(c, 0x112, 0xf); DPP_ADD(d, 0x112, 0xf);                           \
    DPP_ADD(a, 0x114, 0xf); DPP_ADD(b, 0x114, 0xf);                           \
    DPP_ADD(c, 0x114, 0xf); DPP_ADD(d, 0x114, 0xf);                           \
    DPP_ADD(a, 0x118, 0xf); DPP_ADD(b, 0x118, 0xf);                           \
    DPP_ADD(c, 0x118, 0xf); DPP_ADD(d, 0x118, 0xf);                           \
    DPP_ADD(a, 0x142, 0xa); DPP_ADD(b, 0x142, 0xa);                           \
    DPP_ADD(c, 0x142, 0xa); DPP_ADD(d, 0x142, 0xa);                           \
    DPP_ADD(a, 0x143, 0xc); DPP_ADD(b, 0x143, 0xc);                           \
    DPP_ADD(c, 0x143, 0xc); DPP_ADD(d, 0x143, 0xc);                           \
  } while (0)

__device__ __forceinline__ float rl63(float x) {
  return __builtin_bit_cast(
      float, __builtin_amdgcn_readlane(__builtin_bit_cast(int, x), 63));
}

// Safe async prefetch: global -> LDS DMA, no register writeback (the R5-R7
// asm-register loads were unsound: compiler-inserted phi copies read VGPRs
// with in-flight loads). All LDS reads are plain C++ (compiler-managed lgkm).
#define GLL(idx, slot)                                                        \
  __builtin_amdgcn_global_load_lds(                                           \
      (const __attribute__((address_space(1))) void*)(hb + (size_t)(idx) * 64 + lane), \
      (__attribute__((address_space(3))) void*)&kring[(slot)][0], 4, 0, 0)

// One block = one 64-lane wave = one batch chain. Lane i owns row i of M.
//
// Speculative scalar decoupling: per iter t (gate t), the loop-carried path is
//   g_t -> vp' = fma(gu,C_t,a_semi) -> u' = fma(-r,vp',k) -> w -> RED4(w) ->
//   readlane -> g_{t+1}                      (~1 reduction, rest is shadow)
// Shadow work with >= 1 step of slack:
//   a_pre = M_t . k_{t+2}   (speculative, pre-gate dot; corrected by
//                            a_semi = a_pre + gu*C2_t, then + gu'*C_{t+1})
//   M_{t+1} = M_t + gu k_t^T  (LDS re-read of slot t)
//   reductions s2_{t+2}, C_{t+1}=k_{t+1}.k_{t+2}, C2_{t+1}=k_{t+1}.k_{t+3}
//   (interleaved into the same RED4 -> no extra serial depth)
__global__ __launch_bounds__(64, 1)
void delta_mem_seq(const float* __restrict__ h,
                   const float* __restrict__ W,
                   const float* __restrict__ bias,
                   float* __restrict__ out,
                   int L) {
  const int lane = threadIdx.x;
  __shared__ float kring[16][64];  // 16-slot ring, GLL writes slot (t+8)&15
  __shared__ float rbuf[64];
  const float* __restrict__ hb = h + (size_t)blockIdx.x * (size_t)L * 64;
  const int LM1 = L - 1;  // last valid h index; gates t = 0..LM1-1

  v4f m4[16];
#pragma unroll
  for (int q = 0; q < 16; ++q) m4[q] = v4f{0.f, 0.f, 0.f, 0.f};

  // Prologue: fill ring slots 0..7.
#pragma unroll
  for (int i = 0; i < 8; ++i) {
    int idx = (i <= LM1) ? i : LM1;
    GLL(idx, i);
  }
  asm volatile("s_waitcnt vmcnt(0)" ::: "memory");
  __builtin_amdgcn_sched_barrier(0);

  // Own-row elements k_0..k_4 and the 4 prologue reductions.
  float e0 = kring[0][lane];
  float eB = kring[1][lane];  // k_{t+1}
  float eC = kring[2][lane];  // k_{t+2}
  float eD = kring[3][lane];  // k_{t+3}
  float eE = kring[4][lane];  // k_{t+4}
  float p0 = e0 * e0, p1 = eB * eB, p2 = e0 * eB, p3 = e0 * eC;
  WAVE_RED4(p0, p1, p2, p3);
  float s2_cur = rl63(p0);          // s2_0
  float s2_nxt = rl63(p1);          // s2_1
  float C_cur  = rl63(p2);          // C_0  = k_0.k_1
  float C2_cur = rl63(p3);          // C2_0 = k_0.k_2
  float r_nxt = 1.0f / (s2_nxt + EPS);
  float vp = 0.f;      // vp_0 = M_0 k_0 = 0
  float u  = e0;       // u_0 = k_0 - r*0
  float a_semi = 0.f;  // M_0 k_1 = 0

  for (int t = 0; t < LM1; ++t) {
    // ring maintenance: issue k_{t+8}; ensure slots <= t+6 landed.
    int idx = t + 8; if (idx > LM1) idx = LM1;
    GLL(idx, (t + 8) & 15);
    asm volatile("s_waitcnt vmcnt(2)" ::: "memory");
    __builtin_amdgcn_sched_barrier(0);

    float eNew = kring[(t + 5) & 15][lane];  // k_{t+5}, used next iters

    // Bank read: k_{t+2} broadcast (consumed by the dot after RED4 ->
    // lgkm latency hides under the reduction).
    const v4f* kb = (const v4f*)&kring[(t + 2) & 15][0];
    v4f KB[16];
#pragma unroll
    for (int q = 0; q < 16; ++q) KB[q] = kb[q];

    // Products (pure VALU, no memory deps) + the single on-path reduction.
    float w   = u * fmaf(s2_cur, u, 2.0f * vp);  // gate summand (ON PATH)
    float pS  = eC * eC;                          // -> s2_{t+2}
    float pC  = eB * eC;                          // -> C_{t+1}
    float pC2 = eB * eD;                          // -> C2_{t+1}
    WAVE_RED4(w, pS, pC, pC2);
    float z   = rl63(w);
    float nS  = rl63(pS);
    float nC  = rl63(pC);
    float nC2 = rl63(pC2);

    // Gate + the two on-path fmas.
    float gu  = (z > 0.f) ? u : 0.f;
    float vpn = fmaf(gu, C_cur, a_semi);   // vp_{t+1}
    float un  = fmaf(-r_nxt, vpn, eB);     // u_{t+1}

    // Speculative dot: a_pre = M_t . k_{t+2} (KB resolved during RED4).
    v4f ac0 = v4f{0.f, 0.f, 0.f, 0.f}, ac1 = ac0, ac2 = ac0, ac3 = ac0;
#pragma unroll
    for (int q = 0; q < 4; ++q) {
      ac0 = __builtin_elementwise_fma(m4[4 * q + 0], KB[4 * q + 0], ac0);
      ac1 = __builtin_elementwise_fma(m4[4 * q + 1], KB[4 * q + 1], ac1);
      ac2 = __builtin_elementwise_fma(m4[4 * q + 2], KB[4 * q + 2], ac2);
      ac3 = __builtin_elementwise_fma(m4[4 * q + 3], KB[4 * q + 3], ac3);
    }
    v4f acs = (ac0 + ac1) + (ac2 + ac3);
    float a_pre = (acs.x + acs.y) + (acs.z + acs.w);
    float a_semi_n = fmaf(gu, C2_cur, a_pre);  // fold g_t correction

    // M update: M_{t+1} = M_t + gu * k_t^T (re-read slot t from LDS; slot
    // t&15 is overwritten only at iter t+8 -> safe).
    {
      const v4f* ku = (const v4f*)&kring[t & 15][0];
      v4f guv = {gu, gu, gu, gu};
#pragma unroll
      for (int q = 0; q < 16; ++q)
        m4[q] = __builtin_elementwise_fma(guv, ku[q], m4[q]);
    }

    // Rotate scalar state.
    vp = vpn; u = un;
    a_semi = a_semi_n;
    s2_cur = s2_nxt; s2_nxt = nS;
    r_nxt = 1.0f / (nS + EPS);
    C_cur = nC; C2_cur = nC2;
    eB = eC; eC = eD; eD = eE; eE = eNew;
  }

  // vp == read = M_{L-1} @ h[:, L-1]
  rbuf[lane] = vp;
  __syncthreads();  // single wave: orders LDS + drains all pending GLL DMAs

  const v4f* wv = (const v4f*)(W + lane * 64);
  const v4f* rv = (const v4f*)rbuf;
  v4f acc = v4f{0.f, 0.f, 0.f, 0.f};
#pragma unroll
  for (int q = 0; q < 16; ++q)
    acc = __builtin_elementwise_fma(wv[q], rv[q], acc);
  out[(size_t)blockIdx.x * 64 + lane] =
      bias[lane] + ((acc.x + acc.y) + (acc.z + acc.w));
}

extern "C" void kernel_launch(void* const* d_in, const int* in_sizes, int n_in,
                              void* d_out, int out_size, void* d_ws, size_t ws_size,
                              hipStream_t stream) {
  const float* h    = (const float*)d_in[0];
  const float* W    = (const float*)d_in[1];
  const float* bias = (const float*)d_in[2];
  float* out = (float*)d_out;

  const int H = in_sizes[2];            // 64
  const int B = out_size / H;           // 256
  const int L = in_sizes[0] / (B * H);  // 2048

  delta_mem_seq<<<B, 64, 0, stream>>>(h, W, bias, out, L);
}

// Round 9
// 989.674 us; speedup vs baseline: 1.3936x; 1.3936x over previous
//
#include <hip/hip_runtime.h>

typedef float v4f __attribute__((ext_vector_type(4)));
static constexpr float EPS = 1e-6f;

// DPP partial-sum step: x += dpp_move(x); out-of-bounds lanes contribute 0.
#define DPP_ADD(x, ctrl, rmask)                                               \
  x += __builtin_bit_cast(float, __builtin_amdgcn_update_dpp(                 \
           0, __builtin_bit_cast(int, x), ctrl, rmask, 0xf, true))

#define LVL10(ctrl, rmask, a, b, c, d, e, f, g, h, i, j)                      \
  DPP_ADD(a, ctrl, rmask); DPP_ADD(b, ctrl, rmask); DPP_ADD(c, ctrl, rmask);  \
  DPP_ADD(d, ctrl, rmask); DPP_ADD(e, ctrl, rmask); DPP_ADD(f, ctrl, rmask);  \
  DPP_ADD(g, ctrl, rmask); DPP_ADD(h, ctrl, rmask); DPP_ADD(i, ctrl, rmask);  \
  DPP_ADD(j, ctrl, rmask)

// Full wave64 sum of 10 interleaved chains; lane 63 ends with each total.
#define WAVE_RED10(a, b, c, d, e, f, g, h, i, j)                              \
  do {                                                                        \
    LVL10(0x111, 0xf, a, b, c, d, e, f, g, h, i, j);                          \
    LVL10(0x112, 0xf, a, b, c, d, e, f, g, h, i, j);                          \
    LVL10(0x114, 0xf, a, b, c, d, e, f, g, h, i, j);                          \
    LVL10(0x118, 0xf, a, b, c, d, e, f, g, h, i, j);                          \
    LVL10(0x142, 0xa, a, b, c, d, e, f, g, h, i, j);                          \
    LVL10(0x143, 0xc, a, b, c, d, e, f, g, h, i, j);                          \
  } while (0)

#define WAVE_RED1(a)                                                          \
  do {                                                                        \
    DPP_ADD(a, 0x111, 0xf); DPP_ADD(a, 0x112, 0xf); DPP_ADD(a, 0x114, 0xf);  \
    DPP_ADD(a, 0x118, 0xf); DPP_ADD(a, 0x142, 0xa); DPP_ADD(a, 0x143, 0xc);  \
  } while (0)

__device__ __forceinline__ float rl63(float x) {
  return __builtin_bit_cast(
      float, __builtin_amdgcn_readlane(__builtin_bit_cast(int, x), 63));
}

// Async global->LDS DMA (no register writeback -> sound with regalloc).
#define GLL(idx, slot)                                                        \
  __builtin_amdgcn_global_load_lds(                                           \
      (const __attribute__((address_space(1))) void*)(hb + (size_t)(idx) * 64 + lane), \
      (__attribute__((address_space(3))) void*)&kring[(slot)][0], 4, 0, 0)

// asm ds_read_b128, uniform address across lanes -> HW broadcast.
// Early-clobber keeps dst off the live addr reg; every bank is fully drained
// (lgkmcnt(0) + sched_barrier) before ANY use, so no in-flight-writeback
// hazard can occur (R7 lesson).
#define DSR(dst, a, offb)                                                     \
  asm volatile("ds_read_b128 %0, %1 offset:%2"                                \
               : "=&v"(dst) : "v"(a), "i"(offb))

#define RDBANK(B, slot)                                                       \
  do {                                                                        \
    unsigned _a = (unsigned)(unsigned long long)                              \
        (__attribute__((address_space(3))) const float*)&kring[(slot)][0];    \
    DSR(B[0],  _a, 0);   DSR(B[1],  _a, 16);  DSR(B[2],  _a, 32);             \
    DSR(B[3],  _a, 48);  DSR(B[4],  _a, 64);  DSR(B[5],  _a, 80);             \
    DSR(B[6],  _a, 96);  DSR(B[7],  _a, 112); DSR(B[8],  _a, 128);            \
    DSR(B[9],  _a, 144); DSR(B[10], _a, 160); DSR(B[11], _a, 176);            \
    DSR(B[12], _a, 192); DSR(B[13], _a, 208); DSR(B[14], _a, 224);            \
    DSR(B[15], _a, 240);                                                      \
  } while (0)

#define LGKM_DRAIN()                                                          \
  do {                                                                        \
    asm volatile("s_waitcnt lgkmcnt(0)" ::: "memory");                        \
    __builtin_amdgcn_sched_barrier(0);                                        \
  } while (0)

// One block = one wave = one batch chain. Lane i owns row i of M.
// PAIRED-GATE scheme: per macro-iter (steps t, t+1), ONE reduction round of
// 10 interleaved chains: z_t, z^{g=0}_{t+1}, z^{g=1}_{t+1} (speculated on the
// unresolved gate g_t) + 7 Gram entries feeding the next pair. Dots are
// per-pair D1 = M_t k_{t+2}, D2 = M_t k_{t+3} with exact scalar corrections:
//   vp_{t+2} = D1 + g_t (k_t.k_{t+2}) u_t + g_{t+1} (k_{t+1}.k_{t+2}) u_{t+1}
//   A_next   = D2 + g_t (k_t.k_{t+3}) u_t + g_{t+1} (k_{t+1}.k_{t+3}) u_{t+1}
__global__ __launch_bounds__(64, 1)
void delta_mem_seq(const float* __restrict__ h,
                   const float* __restrict__ W,
                   const float* __restrict__ bias,
                   float* __restrict__ out,
                   int L) {
  const int lane = threadIdx.x;
  __shared__ alignas(16) float kring[16][64];
  __shared__ alignas(16) float rbuf[64];
  const float* __restrict__ hb = h + (size_t)blockIdx.x * (size_t)L * 64;
  const int LM1 = L - 1;  // gates t = 0..LM1-1

  v4f m4[16];
#pragma unroll
  for (int q = 0; q < 16; ++q) m4[q] = v4f{0.f, 0.f, 0.f, 0.f};

  // Prologue: fill all 16 ring slots (indexes 0..15 clamped).
#pragma unroll
  for (int i = 0; i < 16; ++i) {
    int idx = (i <= LM1) ? i : LM1;
    GLL(idx, i);
  }
  asm volatile("s_waitcnt vmcnt(0)" ::: "memory");
  __builtin_amdgcn_sched_barrier(0);

  float e0 = kring[0][lane];
  float e1 = kring[1][lane], e2 = kring[2][lane], e3 = kring[3][lane];
  float e4 = kring[4][lane], e5 = kring[5][lane];

  // Prologue reductions: s2_0, s2_1, C_0, C_1, X02, X03, X13.
  float c0 = e0 * e0, c1 = e1 * e1, c2 = e0 * e1, c3 = e1 * e2;
  float c4 = e0 * e2, c5 = e0 * e3, c6 = e1 * e3;
  float c7 = 0.f, c8 = 0.f, c9 = 0.f;
  WAVE_RED10(c0, c1, c2, c3, c4, c5, c6, c7, c8, c9);
  float s2_cur = rl63(c0), s2_nxt = rl63(c1);
  float C_cur = rl63(c2), C_nxt = rl63(c3);
  float X02 = rl63(c4), X03 = rl63(c5), X13 = rl63(c6);
  float r_nxt = 1.0f / (s2_nxt + EPS);
  float vp = 0.f;  // vp_0 = M_0 k_0 = 0
  float u = e0;    // u_0 = k_0
  float A = 0.f;   // M_0 k_1 = 0

  int t = 0;
  for (; t + 1 < LM1; t += 2) {
    // Dot bank k_{t+2}: issue first, latency runs under everything below.
    v4f B2[16];
    RDBANK(B2, (t + 2) & 15);
    asm volatile("s_waitcnt vmcnt(4)" ::: "memory");  // <= t+11 landed
    float eF = kring[(t + 6) & 15][lane];
    float eG = kring[(t + 7) & 15][lane];

    // Per-lane branch speculation + Gram products (pure VALU).
    float vp0 = A;                        // vp_{t+1} if g_t = 0
    float vp1 = fmaf(C_cur, u, A);        // vp_{t+1} if g_t = 1
    float u0 = fmaf(-r_nxt, vp0, e1);
    float u1 = fmaf(-r_nxt, vp1, e1);
    float w  = u  * fmaf(s2_cur, u,  2.0f * vp);    // z_t summand
    float z0 = u0 * fmaf(s2_nxt, u0, 2.0f * vp0);   // z_{t+1} | g=0
    float z1 = u1 * fmaf(s2_nxt, u1, 2.0f * vp1);   // z_{t+1} | g=1
    float pS2a = e2 * e2, pS2b = e3 * e3;           // s2_{t+2}, s2_{t+3}
    float pC2 = e2 * e3, pX02 = e2 * e4, pC3 = e3 * e4;
    float pX03 = e2 * e5, pX13 = e3 * e5;

    LGKM_DRAIN();  // B2 (and eF/eG) landed
    // D1 = M_t . k_{t+2}
    v4f x0 = v4f{0.f, 0.f, 0.f, 0.f}, x1 = x0, x2 = x0, x3 = x0;
#pragma unroll
    for (int q = 0; q < 4; ++q) {
      x0 = __builtin_elementwise_fma(m4[4 * q + 0], B2[4 * q + 0], x0);
      x1 = __builtin_elementwise_fma(m4[4 * q + 1], B2[4 * q + 1], x1);
      x2 = __builtin_elementwise_fma(m4[4 * q + 2], B2[4 * q + 2], x2);
      x3 = __builtin_elementwise_fma(m4[4 * q + 3], B2[4 * q + 3], x3);
    }
    v4f xs = (x0 + x1) + (x2 + x3);
    float D1 = (xs.x + xs.y) + (xs.z + xs.w);

    v4f B3[16];
    RDBANK(B3, (t + 3) & 15);  // latency covered by the reduction round

    WAVE_RED10(w, z0, z1, pS2a, pS2b, pC2, pX02, pC3, pX03, pX13);

    LGKM_DRAIN();  // B3 landed
    // D2 = M_t . k_{t+3}
    v4f y0 = v4f{0.f, 0.f, 0.f, 0.f}, y1 = y0, y2 = y0, y3 = y0;
#pragma unroll
    for (int q = 0; q < 4; ++q) {
      y0 = __builtin_elementwise_fma(m4[4 * q + 0], B3[4 * q + 0], y0);
      y1 = __builtin_elementwise_fma(m4[4 * q + 1], B3[4 * q + 1], y1);
      y2 = __builtin_elementwise_fma(m4[4 * q + 2], B3[4 * q + 2], y2);
      y3 = __builtin_elementwise_fma(m4[4 * q + 3], B3[4 * q + 3], y3);
    }
    v4f ys = (y0 + y1) + (y2 + y3);
    float D2 = (ys.x + ys.y) + (ys.z + ys.w);

    v4f B0[16];
    RDBANK(B0, t & 15);  // latency covered by readlanes + gate chain

    // Readlanes + gate resolution.
    float zt = rl63(w);
    float z0s = rl63(z0), z1s = rl63(z1);
    float s2a = rl63(pS2a), s2b = rl63(pS2b);
    float C2s = rl63(pC2), X02n = rl63(pX02), C3s = rl63(pC3);
    float X03n = rl63(pX03), X13n = rl63(pX13);
    bool gt = zt > 0.f;
    float zsel = gt ? z1s : z0s;
    bool gt1 = zsel > 0.f;
    float ga = gt ? u : 0.f;                // g_t * u_t
    float usel = gt ? u1 : u0;              // u_{t+1} resolved
    float gb = gt1 ? usel : 0.f;            // g_{t+1} * u_{t+1}
    float r2 = 1.0f / (s2a + EPS);          // r_{t+2} (off-path)

    LGKM_DRAIN();  // B0 landed
    v4f gav = {ga, ga, ga, ga};
#pragma unroll
    for (int q = 0; q < 16; ++q)            // M += g_t u_t k_t^T
      m4[q] = __builtin_elementwise_fma(gav, B0[q], m4[q]);

    v4f B1[16];
    RDBANK(B1, (t + 1) & 15);  // latency covered by resolves below

    // Next-pair state (corrections applied to the speculative dots).
    float vp_n = fmaf(C_nxt, gb, fmaf(X02, ga, D1));  // vp_{t+2}
    float A_n  = fmaf(X13,  gb, fmaf(X03, ga, D2));   // M_{t+2} k_{t+3} base
    float u_n  = fmaf(-r2, vp_n, e2);                 // u_{t+2}

    LGKM_DRAIN();  // B1 landed; ALL bank reads of slots t, t+1 complete
    // -> safe to refill those slots with indexes t+16, t+17 now.
    {
      int i0 = t + 16; if (i0 > LM1) i0 = LM1;
      int i1 = t + 17; if (i1 > LM1) i1 = LM1;
      GLL(i0, (t + 16) & 15);
      GLL(i1, (t + 17) & 15);
    }
    v4f gbv = {gb, gb, gb, gb};
#pragma unroll
    for (int q = 0; q < 16; ++q)            // M += g_{t+1} u_{t+1} k_{t+1}^T
      m4[q] = __builtin_elementwise_fma(gbv, B1[q], m4[q]);

    // Rotate state.
    vp = vp_n; u = u_n; A = A_n;
    s2_cur = s2a; s2_nxt = s2b; r_nxt = 1.0f / (s2b + EPS);
    C_cur = C2s; C_nxt = C3s; X02 = X02n; X03 = X03n; X13 = X13n;
    e1 = e3; e2 = e4; e3 = e5; e4 = eF; e5 = eG;
  }

  if (t < LM1) {  // odd leftover gate (t = LM1-1): no M-update needed
    float w = u * fmaf(s2_cur, u, 2.0f * vp);
    WAVE_RED1(w);
    float zt = rl63(w);
    float coef = (zt > 0.f) ? C_cur : 0.f;
    vp = fmaf(coef, u, A);  // read = M_L k_{L-1}
  }

  // Drain pending GLL DMAs before LDS could be reallocated at endpgm.
  asm volatile("s_waitcnt vmcnt(0)" ::: "memory");
  __builtin_amdgcn_sched_barrier(0);

  rbuf[lane] = vp;
  __syncthreads();

  const v4f* wv = (const v4f*)(W + lane * 64);
  const v4f* rv = (const v4f*)rbuf;
  v4f acc = v4f{0.f, 0.f, 0.f, 0.f};
#pragma unroll
  for (int q = 0; q < 16; ++q)
    acc = __builtin_elementwise_fma(wv[q], rv[q], acc);
  out[(size_t)blockIdx.x * 64 + lane] =
      bias[lane] + ((acc.x + acc.y) + (acc.z + acc.w));
}

extern "C" void kernel_launch(void* const* d_in, const int* in_sizes, int n_in,
                              void* d_out, int out_size, void* d_ws, size_t ws_size,
                              hipStream_t stream) {
  const float* h    = (const float*)d_in[0];
  const float* W    = (const float*)d_in[1];
  const float* bias = (const float*)d_in[2];
  float* out = (float*)d_out;

  const int H = in_sizes[2];            // 64
  const int B = out_size / H;           // 256
  const int L = in_sizes[0] / (B * H);  // 2048

  delta_mem_seq<<<B, 64, 0, stream>>>(h, W, bias, out, L);
}

// Round 10
// 810.813 us; speedup vs baseline: 1.7010x; 1.2206x over previous
//
#include <hip/hip_runtime.h>

typedef float v4f __attribute__((ext_vector_type(4)));
static constexpr float EPS = 1e-6f;

// DPP partial-sum step: x += dpp_move(x); out-of-bounds lanes contribute 0.
#define DPP_ADD(x, ctrl, rmask)                                               \
  x += __builtin_bit_cast(float, __builtin_amdgcn_update_dpp(                 \
           0, __builtin_bit_cast(int, x), ctrl, rmask, 0xf, true))

#define LVL10(ctrl, rmask, a, b, c, d, e, f, g, h, i, j)                      \
  DPP_ADD(a, ctrl, rmask); DPP_ADD(b, ctrl, rmask); DPP_ADD(c, ctrl, rmask);  \
  DPP_ADD(d, ctrl, rmask); DPP_ADD(e, ctrl, rmask); DPP_ADD(f, ctrl, rmask);  \
  DPP_ADD(g, ctrl, rmask); DPP_ADD(h, ctrl, rmask); DPP_ADD(i, ctrl, rmask);  \
  DPP_ADD(j, ctrl, rmask)

// Full wave64 sum of 10 interleaved chains; lane 63 ends with each total.
#define WAVE_RED10(a, b, c, d, e, f, g, h, i, j)                              \
  do {                                                                        \
    LVL10(0x111, 0xf, a, b, c, d, e, f, g, h, i, j);                          \
    LVL10(0x112, 0xf, a, b, c, d, e, f, g, h, i, j);                          \
    LVL10(0x114, 0xf, a, b, c, d, e, f, g, h, i, j);                          \
    LVL10(0x118, 0xf, a, b, c, d, e, f, g, h, i, j);                          \
    LVL10(0x142, 0xa, a, b, c, d, e, f, g, h, i, j);                          \
    LVL10(0x143, 0xc, a, b, c, d, e, f, g, h, i, j);                          \
  } while (0)

#define WAVE_RED1(a)                                                          \
  do {                                                                        \
    DPP_ADD(a, 0x111, 0xf); DPP_ADD(a, 0x112, 0xf); DPP_ADD(a, 0x114, 0xf);  \
    DPP_ADD(a, 0x118, 0xf); DPP_ADD(a, 0x142, 0xa); DPP_ADD(a, 0x143, 0xc);  \
  } while (0)

__device__ __forceinline__ float rl63(float x) {
  return __builtin_bit_cast(
      float, __builtin_amdgcn_readlane(__builtin_bit_cast(int, x), 63));
}

// Async global->LDS DMA (no register writeback -> sound with regalloc).
#define GLL(idx, slot)                                                        \
  __builtin_amdgcn_global_load_lds(                                           \
      (const __attribute__((address_space(1))) void*)(hb + (size_t)(idx) * 64 + lane), \
      (__attribute__((address_space(3))) void*)&kring[(slot)][0], 4, 0, 0)

// asm ds_read_b128, wave-uniform address -> HW broadcast. Early-clobber dst;
// every bank fully drained (counted lgkm + sched_barrier) before ANY use.
#define DSR(dst, a, offb)                                                     \
  asm volatile("ds_read_b128 %0, %1 offset:%2"                                \
               : "=&v"(dst) : "v"(a), "i"(offb))

// 8 reads = this wave's 32-col slice of one k vector.
#define DSR8(B, slot)                                                         \
  do {                                                                        \
    unsigned _a = (unsigned)(unsigned long long)                              \
        (__attribute__((address_space(3))) const float*)&kring[(slot)][slice];\
    DSR(B[0], _a, 0);   DSR(B[1], _a, 16);  DSR(B[2], _a, 32);                \
    DSR(B[3], _a, 48);  DSR(B[4], _a, 64);  DSR(B[5], _a, 80);                \
    DSR(B[6], _a, 96);  DSR(B[7], _a, 112);                                   \
  } while (0)

#define SB __builtin_amdgcn_sched_barrier(0)
// FIFO rule: after issuing K of my ds-reads, waiting lgkmcnt(K-m) guarantees
// my first m landed, regardless of compiler ds-ops before/after the bracket.
#define WAIT_LGKM(n)                                                          \
  do { asm volatile("s_waitcnt lgkmcnt(" #n ")" ::: "memory"); SB; } while (0)
#define WAIT_VM(n)                                                            \
  do { asm volatile("s_waitcnt vmcnt(" #n ")" ::: "memory"); SB; } while (0)

// One block = 2 waves = one batch chain. Lane i owns row i of M; wave w owns
// columns [32w, 32w+32). Scalar/gate state is replicated in both waves (same
// inputs, same op order -> bitwise identical). Only dots and M-updates are
// split; partial dots are exchanged through LDS once per pair.
// PAIRED-GATE algebra identical to R9 (passed, absmax 6.5).
__global__ __launch_bounds__(128, 1)
void delta_mem_seq(const float* __restrict__ h,
                   const float* __restrict__ W,
                   const float* __restrict__ bias,
                   float* __restrict__ out,
                   int L) {
  const int tid = threadIdx.x;
  const int w = tid >> 6;
  const int lane = tid & 63;
  const int slice = w << 5;
  __shared__ alignas(16) float kring[32][64];   // 32-slot ring
  __shared__ float2 pdx[2][2][64];              // [parity][wave][row]
  __shared__ alignas(16) float rbuf[64];
  const float* __restrict__ hb = h + (size_t)blockIdx.x * (size_t)L * 64;
  const int LM1 = L - 1;  // gates t = 0..LM1-1

  v4f m4[8];  // M[lane][32w .. 32w+31]
#pragma unroll
  for (int q = 0; q < 8; ++q) m4[q] = v4f{0.f, 0.f, 0.f, 0.f};

  // Prologue: fill ring slots 0..15 (both waves issue duplicates -> vmcnt
  // accounting stays wave-local; same bytes to same LDS = benign).
#pragma unroll
  for (int i = 0; i < 16; ++i) {
    int idx = (i <= LM1) ? i : LM1;
    GLL(idx, i);
  }
  WAIT_VM(0);

  float e0 = kring[0][lane];
  float e1 = kring[1][lane], e2 = kring[2][lane], e3 = kring[3][lane];
  float e4 = kring[4][lane], e5 = kring[5][lane];

  // Prologue reductions: s2_0, s2_1, C_0, C_1, X02, X03, X13.
  float c0 = e0 * e0, c1 = e1 * e1, c2 = e0 * e1, c3 = e1 * e2;
  float c4 = e0 * e2, c5 = e0 * e3, c6 = e1 * e3;
  float c7 = 0.f, c8 = 0.f, c9 = 0.f;
  WAVE_RED10(c0, c1, c2, c3, c4, c5, c6, c7, c8, c9);
  float s2_cur = rl63(c0), s2_nxt = rl63(c1);
  float C_cur = rl63(c2), C_nxt = rl63(c3);
  float X02 = rl63(c4), X03 = rl63(c5), X13 = rl63(c6);
  float r_nxt = 1.0f / (s2_nxt + EPS);
  float vp = 0.f;  // vp_0 = M_0 k_0 = 0
  float u = e0;    // u_0 = k_0
  float A = 0.f;   // M_0 k_1 = 0
  int par = 0;

  int t = 0;
  for (; t + 1 < LM1; t += 2) {
    WAIT_VM(12);  // ring slots <= t+3 landed (issued >= 13 pairs ago)

    v4f B2[8], B3[8];
    SB;
    DSR8(B2, (t + 2) & 31);
    DSR8(B3, (t + 3) & 31);   // K = 16 of my lgkm entries
    SB;

    // Per-lane branch speculation + Gram products (pure VALU, fills latency).
    float vp0 = A;                        // vp_{t+1} if g_t = 0
    float vp1 = fmaf(C_cur, u, A);        // vp_{t+1} if g_t = 1
    float u0 = fmaf(-r_nxt, vp0, e1);
    float u1 = fmaf(-r_nxt, vp1, e1);
    float wz = u  * fmaf(s2_cur, u,  2.0f * vp);    // z_t summand
    float z0 = u0 * fmaf(s2_nxt, u0, 2.0f * vp0);   // z_{t+1} | g=0
    float z1 = u1 * fmaf(s2_nxt, u1, 2.0f * vp1);   // z_{t+1} | g=1
    float pS2a = e2 * e2, pS2b = e3 * e3;           // s2_{t+2}, s2_{t+3}
    float pC2 = e2 * e3, pX02 = e2 * e4, pC3 = e3 * e4;
    float pX03 = e2 * e5, pX13 = e3 * e5;

    WAIT_LGKM(8);  // B2 landed
    float D1own;
    {
      v4f x0 = v4f{0.f, 0.f, 0.f, 0.f}, x1 = x0, x2 = x0, x3 = x0;
      x0 = __builtin_elementwise_fma(m4[0], B2[0], x0);
      x1 = __builtin_elementwise_fma(m4[1], B2[1], x1);
      x2 = __builtin_elementwise_fma(m4[2], B2[2], x2);
      x3 = __builtin_elementwise_fma(m4[3], B2[3], x3);
      x0 = __builtin_elementwise_fma(m4[4], B2[4], x0);
      x1 = __builtin_elementwise_fma(m4[5], B2[5], x1);
      x2 = __builtin_elementwise_fma(m4[6], B2[6], x2);
      x3 = __builtin_elementwise_fma(m4[7], B2[7], x3);
      v4f xs = (x0 + x1) + (x2 + x3);
      D1own = (xs.x + xs.y) + (xs.z + xs.w);
    }
    WAIT_LGKM(0);  // B3 landed
    float D2own;
    {
      v4f y0 = v4f{0.f, 0.f, 0.f, 0.f}, y1 = y0, y2 = y0, y3 = y0;
      y0 = __builtin_elementwise_fma(m4[0], B3[0], y0);
      y1 = __builtin_elementwise_fma(m4[1], B3[1], y1);
      y2 = __builtin_elementwise_fma(m4[2], B3[2], y2);
      y3 = __builtin_elementwise_fma(m4[3], B3[3], y3);
      y0 = __builtin_elementwise_fma(m4[4], B3[4], y0);
      y1 = __builtin_elementwise_fma(m4[5], B3[5], y1);
      y2 = __builtin_elementwise_fma(m4[6], B3[6], y2);
      y3 = __builtin_elementwise_fma(m4[7], B3[7], y3);
      v4f ys = (y0 + y1) + (y2 + y3);
      D2own = (ys.x + ys.y) + (ys.z + ys.w);
    }

    pdx[par][w][lane] = make_float2(D1own, D2own);  // exchange write

    WAVE_RED10(wz, z0, z1, pS2a, pS2b, pC2, pX02, pC3, pX03, pX13);

    asm volatile("s_waitcnt lgkmcnt(0)" ::: "memory");  // write visible
    __builtin_amdgcn_s_barrier();                       // partner's too
    SB;

    float2 po = pdx[par][w ^ 1][lane];  // partner partials

    v4f B0[8], B1[8];
    SB;
    DSR8(B0, t & 31);
    DSR8(B1, (t + 1) & 31);   // K = 16; latency hidden by resolves below
    SB;

    // Readlanes + gate resolution (SALU-heavy, overlaps B0/B1 latency).
    float zt = rl63(wz);
    float z0s = rl63(z0), z1s = rl63(z1);
    float s2a = rl63(pS2a), s2b = rl63(pS2b);
    float C2s = rl63(pC2), X02n = rl63(pX02), C3s = rl63(pC3);
    float X03n = rl63(pX03), X13n = rl63(pX13);
    bool gt = zt > 0.f;
    float zsel = gt ? z1s : z0s;
    bool gt1 = zsel > 0.f;
    float ga = gt ? u : 0.f;                // g_t * u_t
    float usel = gt ? u1 : u0;              // u_{t+1} resolved
    float gb = gt1 ? usel : 0.f;            // g_{t+1} * u_{t+1}
    float r2 = 1.0f / (s2a + EPS);

    float D1 = D1own + po.x;
    float D2 = D2own + po.y;
    float vp_n = fmaf(C_nxt, gb, fmaf(X02, ga, D1));  // vp_{t+2}
    float A_n  = fmaf(X13,  gb, fmaf(X03, ga, D2));   // M_{t+2} k_{t+3}
    float u_n  = fmaf(-r2, vp_n, e2);                 // u_{t+2}

    WAIT_LGKM(8);  // B0 landed
    {
      v4f gav = {ga, ga, ga, ga};
#pragma unroll
      for (int q = 0; q < 8; ++q)           // M += g_t u_t k_t^T (slice)
        m4[q] = __builtin_elementwise_fma(gav, B0[q], m4[q]);
    }
    WAIT_LGKM(0);  // B1 landed
    {
      v4f gbv = {gb, gb, gb, gb};
#pragma unroll
      for (int q = 0; q < 8; ++q)           // M += g_{t+1} u_{t+1} k_{t+1}^T
        m4[q] = __builtin_elementwise_fma(gbv, B1[q], m4[q]);
    }

    WAIT_VM(8);  // ring slots <= t+7 landed
    float eF = kring[(t + 6) & 31][lane];
    float eG = kring[(t + 7) & 31][lane];
    {
      int i0 = t + 16; if (i0 > LM1) i0 = LM1;
      int i1 = t + 17; if (i1 > LM1) i1 = LM1;
      GLL(i0, (t + 16) & 31);   // >= 9 slots from the read window: race-free
      GLL(i1, (t + 17) & 31);
    }

    // Rotate state.
    vp = vp_n; u = u_n; A = A_n;
    s2_cur = s2a; s2_nxt = s2b; r_nxt = 1.0f / (s2b + EPS);
    C_cur = C2s; C_nxt = C3s; X02 = X02n; X03 = X03n; X13 = X13n;
    e1 = e3; e2 = e4; e3 = e5; e4 = eF; e5 = eG;
    par ^= 1;
  }

  if (t < LM1) {  // odd leftover gate: no M-update needed
    float wz = u * fmaf(s2_cur, u, 2.0f * vp);
    WAVE_RED1(wz);
    float zt = rl63(wz);
    float coef = (zt > 0.f) ? C_cur : 0.f;
    vp = fmaf(coef, u, A);  // read = M_L k_{L-1}
  }

  // Drain pending GLL DMAs before LDS deallocation at endpgm.
  WAIT_VM(0);

  if (w == 0) rbuf[lane] = vp;
  __syncthreads();

  if (w == 0) {
    const v4f* wv = (const v4f*)(W + lane * 64);
    const v4f* rv = (const v4f*)rbuf;
    v4f acc = v4f{0.f, 0.f, 0.f, 0.f};
#pragma unroll
    for (int q = 0; q < 16; ++q)
      acc = __builtin_elementwise_fma(wv[q], rv[q], acc);
    out[(size_t)blockIdx.x * 64 + lane] =
        bias[lane] + ((acc.x + acc.y) + (acc.z + acc.w));
  }
}

extern "C" void kernel_launch(void* const* d_in, const int* in_sizes, int n_in,
                              void* d_out, int out_size, void* d_ws, size_t ws_size,
                              hipStream_t stream) {
  const float* h    = (const float*)d_in[0];
  const float* W    = (const float*)d_in[1];
  const float* bias = (const float*)d_in[2];
  float* out = (float*)d_out;

  const int H = in_sizes[2];            // 64
  const int B = out_size / H;           // 256
  const int L = in_sizes[0] / (B * H);  // 2048

  delta_mem_seq<<<B, 128, 0, stream>>>(h, W, bias, out, L);
}